// Round 3
// baseline (196.089 us; speedup 1.0000x reference)
//
#include <hip/hip_runtime.h>
#include <hip/hip_bf16.h>

typedef _Float16 f16x8 __attribute__((ext_vector_type(8)));
typedef _Float16 f16x4 __attribute__((ext_vector_type(4)));
typedef __fp16 fp16x2 __attribute__((ext_vector_type(2)));
typedef float f32x4 __attribute__((ext_vector_type(4)));

#define BATCH 4
#define SEQ 4096
#define EMB 1024
#define HEAD 64

// Async global->LDS, 16B per lane. LDS dest is WAVE-UNIFORM base; HW adds
// lane*16. Global src is per-lane (we make it base + lane*16 = coalesced).
__device__ __forceinline__ void async_copy16(const void* gsrc, void* ldst) {
  __builtin_amdgcn_global_load_lds(
      (const __attribute__((address_space(1))) void*)gsrc,
      (__attribute__((address_space(3))) void*)ldst,
      16, 0, 0);
}

// ---------------------------------------------------------------------------
// Kernel 1: weights -> glds-tiled WT (unchanged).
// ---------------------------------------------------------------------------
__global__ __launch_bounds__(256) void wtrans_kernel(
    const float* __restrict__ Wk, const float* __restrict__ Wq,
    const float* __restrict__ Wv, _Float16* __restrict__ WT) {
  int id = blockIdx.x * 256 + threadIdx.x;   // 0 .. 24575 (unit index)
  int step = id / 1536;
  int rem = id - step * 1536;
  int G = rem / 192;
  int n = rem - G * 192;
  int sel = n >> 6;
  int col = n & 63;
  const float* src = (sel == 0) ? Wq : (sel == 1) ? Wk : Wv;
  const float scale = (sel == 0) ? 0.03125f : 1.0f;
  f16x8 u;
#pragma unroll
  for (int j = 0; j < 8; ++j) {
    int k = step * 64 + G * 8 + j;
    u[j] = (_Float16)(src[k * 64 + col] * scale);
  }
  *(f16x8*)(WT + (size_t)id * 8) = u;
}

// ---------------------------------------------------------------------------
// Kernel 2: QKV projection (unchanged).
// ---------------------------------------------------------------------------
__global__ __launch_bounds__(256) void proj_kernel(
    const float* __restrict__ x, const _Float16* __restrict__ WT,
    _Float16* __restrict__ Qh, _Float16* __restrict__ KT,
    _Float16* __restrict__ VT) {
  __shared__ _Float16 wtl[2][12288];   // 2 x 24 KB, unit u = G*192 + n
  const int tid = threadIdx.x;
  const int wave = tid >> 6;
  const int lane = tid & 63;
  const int quad = lane >> 4;
  const int l16 = lane & 15;
  const int wm = wave & 1;
  const int wn = wave >> 1;
  const int rowblk = blockIdx.x * 32;

  const float* xr = x + (size_t)(rowblk + wm * 16 + l16) * EMB + quad * 8;

  f32x4 acc[6];
#pragma unroll
  for (int t = 0; t < 6; ++t) acc[t] = (f32x4){0.f, 0.f, 0.f, 0.f};

#pragma unroll
  for (int i = 0; i < 6; ++i) {
    const int c = wave * 6 + i;
    async_copy16(WT + (size_t)c * 512 + lane * 8, (char*)&wtl[0][0] + c * 1024);
  }
  float4 xa = *(const float4*)(xr);
  float4 xb = *(const float4*)(xr + 4);
  float4 xc = *(const float4*)(xr + 32);
  float4 xd = *(const float4*)(xr + 36);
  __syncthreads();

  int p = 0;
  for (int step = 0; step < 16; ++step) {
    if (step < 15) {
      const _Float16* wsrc = WT + (size_t)(step + 1) * 12288;
#pragma unroll
      for (int i = 0; i < 6; ++i) {
        const int c = wave * 6 + i;
        async_copy16(wsrc + (size_t)c * 512 + lane * 8,
                     (char*)&wtl[p ^ 1][0] + c * 1024);
      }
    }
    fp16x2 p0 = __builtin_amdgcn_cvt_pkrtz(xa.x, xa.y);
    fp16x2 p1 = __builtin_amdgcn_cvt_pkrtz(xa.z, xa.w);
    fp16x2 p2 = __builtin_amdgcn_cvt_pkrtz(xb.x, xb.y);
    fp16x2 p3 = __builtin_amdgcn_cvt_pkrtz(xb.z, xb.w);
    f16x8 af0, af1;
    af0[0] = (_Float16)p0[0]; af0[1] = (_Float16)p0[1];
    af0[2] = (_Float16)p1[0]; af0[3] = (_Float16)p1[1];
    af0[4] = (_Float16)p2[0]; af0[5] = (_Float16)p2[1];
    af0[6] = (_Float16)p3[0]; af0[7] = (_Float16)p3[1];
    p0 = __builtin_amdgcn_cvt_pkrtz(xc.x, xc.y);
    p1 = __builtin_amdgcn_cvt_pkrtz(xc.z, xc.w);
    p2 = __builtin_amdgcn_cvt_pkrtz(xd.x, xd.y);
    p3 = __builtin_amdgcn_cvt_pkrtz(xd.z, xd.w);
    af1[0] = (_Float16)p0[0]; af1[1] = (_Float16)p0[1];
    af1[2] = (_Float16)p1[0]; af1[3] = (_Float16)p1[1];
    af1[4] = (_Float16)p2[0]; af1[5] = (_Float16)p2[1];
    af1[6] = (_Float16)p3[0]; af1[7] = (_Float16)p3[1];
    if (step < 15) {
      const float* xn = xr + (step + 1) * 64;
      xa = *(const float4*)(xn);
      xb = *(const float4*)(xn + 4);
      xc = *(const float4*)(xn + 32);
      xd = *(const float4*)(xn + 36);
    }
#pragma unroll
    for (int t = 0; t < 6; ++t) {
      const int n = wn * 96 + t * 16 + l16;
      const f16x8 b0 = *(const f16x8*)&wtl[p][(size_t)((0 * 4 + quad) * 192 + n) * 8];
      const f16x8 b1 = *(const f16x8*)&wtl[p][(size_t)((1 * 4 + quad) * 192 + n) * 8];
      acc[t] = __builtin_amdgcn_mfma_f32_16x16x32_f16(af0, b0, acc[t], 0, 0, 0);
      acc[t] = __builtin_amdgcn_mfma_f32_16x16x32_f16(af1, b1, acc[t], 0, 0, 0);
    }
    __syncthreads();
    p ^= 1;
  }

  const int rowbase = rowblk + wm * 16;
  const int b = rowbase >> 12;
  const int trbase = (rowbase & 4095) + quad * 4;
#pragma unroll
  for (int t = 0; t < 6; ++t) {
    const int g = wn * 6 + t;
    if (g < 4) {                         // Q row-major (scaled via Wq)
      const int h = g * 16 + l16;
#pragma unroll
      for (int r = 0; r < 4; ++r)
        Qh[(size_t)(rowbase + quad * 4 + r) * HEAD + h] = (_Float16)acc[t][r];
    } else if (g < 8) {                  // K -> KT[b][kt][G=h/8][key][h%8]
      const int h = (g - 4) * 16 + l16;
#pragma unroll
      for (int r = 0; r < 4; ++r) {
        const int t0 = trbase + r;
        const size_t ad = ((size_t)((b * 64 + (t0 >> 6)) * 8 + (h >> 3)) * 64 +
                           (t0 & 63)) * 8 + (h & 7);
        KT[ad] = (_Float16)acc[t][r];
      }
    } else {                             // V -> VT[b][kt][Gk=keygrp][h][key%8]
      const int h = (g - 8) * 16 + l16;
      f16x4 pk;
      pk[0] = (_Float16)acc[t][0]; pk[1] = (_Float16)acc[t][1];
      pk[2] = (_Float16)acc[t][2]; pk[3] = (_Float16)acc[t][3];
      const size_t ad = ((size_t)((b * 64 + (trbase >> 6)) * 8 + ((trbase & 63) >> 3)) * 512) +
                        (size_t)h * 8 + (trbase & 7);
      *(f16x4*)(VT + ad) = pk;
    }
  }
}

// ---------------------------------------------------------------------------
// Kernel 3: causal flash attention, wave-private q-tiles.
// Block = 2 waves (128 thr). Wave w owns 16-row tile t = 2i+w (i = blk>>2),
// rows qb = 32i + 16w; both tiles share nkt = i/2+1, so the single
// kv-double-buffer barrier is uniform. Per step each wave does the FULL
// 64-key pipeline privately: QK (8 MFMA) -> mask/exp -> P to wave-private
// LDS (stride 68 halves: write banks quad*8+l16/2 -> 32 distinct, no
// conflict) -> PV (8 MFMA, k=64). No cross-wave P barrier, no O/l combine;
// Q frags hoisted out of the loop. Grid 512, all blocks resident;
// makespan = 64-step heaviest block. b = blockIdx&3 -> one batch per
// XCD pair (KV 4MB L2-resident).
// ---------------------------------------------------------------------------
__global__ __launch_bounds__(128) void flash_kernel(
    const _Float16* __restrict__ Qh, const _Float16* __restrict__ KT,
    const _Float16* __restrict__ VT, float* __restrict__ out) {
  __shared__ _Float16 kv[2][8192];     // 16 KB/buf: K units 0..511, V 512..1023
  __shared__ _Float16 myp[2][16 * 68]; // wave-private P, row stride 68 halves
  const int tid = threadIdx.x;
  const int w = tid >> 6;
  const int lane = tid & 63;
  const int quad = lane >> 4;
  const int l16 = lane & 15;
  const int b = blockIdx.x & 3;
  const int i = blockIdx.x >> 2;       // 0..127
  const int qb = i * 32 + w * 16;      // wave's 16-row tile base
  const int nkt = (i >> 1) + 1;

  const _Float16* Q = Qh + (size_t)b * SEQ * HEAD;
  const f32x4 zero = {0.f, 0.f, 0.f, 0.f};
  _Float16* mp = &myp[w][0];

  // Q A-frags for the whole tile, loaded once
  const f16x8 aq0 = *(const f16x8*)(Q + (size_t)(qb + l16) * HEAD + quad * 8);
  const f16x8 aq1 = *(const f16x8*)(Q + (size_t)(qb + l16) * HEAD + 32 + quad * 8);
  const int qrow = qb + quad * 4;      // +r

  f32x4 oc[4];
#pragma unroll
  for (int m = 0; m < 4; ++m) oc[m] = zero;
  float lacc[4] = {0.f, 0.f, 0.f, 0.f};

  // stage tile 0 into buf 0: 16 chunks (8 K + 8 V), 8 per wave
  {
    const size_t tb = (size_t)(b * 64 + 0) * 8;
#pragma unroll
    for (int c0 = 0; c0 < 8; ++c0) {
      const int c = w * 8 + c0;
      const _Float16* src = (c < 8) ? (KT + (tb + c) * 512 + lane * 8)
                                    : (VT + (tb + (c - 8)) * 512 + lane * 8);
      async_copy16(src, (char*)&kv[0][0] + c * 1024);
    }
  }
  __syncthreads();

  int p = 0;
  for (int kt = 0; kt < nkt; ++kt) {
    if (kt + 1 < nkt) {                // stage next tile (overlaps compute)
      const size_t tb = (size_t)(b * 64 + kt + 1) * 8;
#pragma unroll
      for (int c0 = 0; c0 < 8; ++c0) {
        const int c = w * 8 + c0;
        const _Float16* src = (c < 8) ? (KT + (tb + c) * 512 + lane * 8)
                                      : (VT + (tb + (c - 8)) * 512 + lane * 8);
        async_copy16(src, (char*)&kv[p ^ 1][0] + c * 1024);
      }
    }

    // QK: full 64 keys, 4 key-subtiles x (2 MFMA over h=64)
    f32x4 sc[4];
#pragma unroll
    for (int s = 0; s < 4; ++s) {
      const f16x8 kb0 = *(const f16x8*)&kv[p][(size_t)((0 + quad) * 64 + s * 16 + l16) * 8];
      const f16x8 kb1 = *(const f16x8*)&kv[p][(size_t)((4 + quad) * 64 + s * 16 + l16) * 8];
      sc[s] = __builtin_amdgcn_mfma_f32_16x16x32_f16(aq0, kb0, zero, 0, 0, 0);
      sc[s] = __builtin_amdgcn_mfma_f32_16x16x32_f16(aq1, kb1, sc[s], 0, 0, 0);
    }

    // mask (diagonal step only) + exp + wave-private P write
    const int kbase = kt * 64;
    if (kt == nkt - 1) {
#pragma unroll
      for (int s = 0; s < 4; ++s) {
#pragma unroll
        for (int r = 0; r < 4; ++r) {
          const float pv = (kbase + s * 16 + l16 > qrow + r) ? 0.f : __expf(sc[s][r]);
          lacc[r] += pv;
          mp[(quad * 4 + r) * 68 + s * 16 + l16] = (_Float16)pv;
        }
      }
    } else {
#pragma unroll
      for (int s = 0; s < 4; ++s) {
#pragma unroll
        for (int r = 0; r < 4; ++r) {
          const float pv = __expf(sc[s][r]);
          lacc[r] += pv;
          mp[(quad * 4 + r) * 68 + s * 16 + l16] = (_Float16)pv;
        }
      }
    }

    // P A-frags (wave-private round trip, lgkmcnt-ordered, no barrier)
    const f16x8 ap0 = *(const f16x8*)(mp + l16 * 68 + quad * 8);
    const f16x8 ap1 = *(const f16x8*)(mp + l16 * 68 + 32 + quad * 8);

    // PV: 4 h-subtiles x (2 MFMA over k=64)
#pragma unroll
    for (int m = 0; m < 4; ++m) {
      const f16x8 bv0 = *(const f16x8*)&kv[p][4096 + (size_t)((0 + quad) * 64 + m * 16 + l16) * 8];
      const f16x8 bv1 = *(const f16x8*)&kv[p][4096 + (size_t)((4 + quad) * 64 + m * 16 + l16) * 8];
      oc[m] = __builtin_amdgcn_mfma_f32_16x16x32_f16(ap0, bv0, oc[m], 0, 0, 0);
      oc[m] = __builtin_amdgcn_mfma_f32_16x16x32_f16(ap1, bv1, oc[m], 0, 0, 0);
    }

    __syncthreads();                   // kv[p] consumed; kv[p^1] staged
    p ^= 1;
  }

  // wave-local row sums (reduce over l16 within the quad group) + write
#pragma unroll
  for (int r = 0; r < 4; ++r) {
    float l = lacc[r];
    l += __shfl_xor(l, 1);
    l += __shfl_xor(l, 2);
    l += __shfl_xor(l, 4);
    l += __shfl_xor(l, 8);
    const float inv = 1.0f / l;
    float* op = out + ((size_t)b * SEQ + qb + quad * 4 + r) * HEAD + l16;
#pragma unroll
    for (int m = 0; m < 4; ++m) op[m * 16] = oc[m][r] * inv;
  }
}

extern "C" void kernel_launch(void* const* d_in, const int* in_sizes, int n_in,
                              void* d_out, int out_size, void* d_ws, size_t ws_size,
                              hipStream_t stream) {
  const float* x  = (const float*)d_in[0];
  const float* Wk = (const float*)d_in[1];
  const float* Wq = (const float*)d_in[2];
  const float* Wv = (const float*)d_in[3];
  float* out = (float*)d_out;

  // ws layout: Qh[0,2MB) KT[2MB,4MB) VT[4MB,6MB) WT[6MB,6.375MB)
  char* ws = (char*)d_ws;
  _Float16* Qh = (_Float16*)(ws);
  _Float16* KT = (_Float16*)(ws + (size_t)2 * 1024 * 1024);
  _Float16* VT = (_Float16*)(ws + (size_t)4 * 1024 * 1024);
  _Float16* WT = (_Float16*)(ws + (size_t)6 * 1024 * 1024);

  wtrans_kernel<<<96, 256, 0, stream>>>(Wk, Wq, Wv, WT);
  proj_kernel<<<512, 256, 0, stream>>>(x, WT, Qh, KT, VT);
  flash_kernel<<<512, 128, 0, stream>>>(Qh, KT, VT, out);
}

// Round 4
// 143.709 us; speedup vs baseline: 1.3645x; 1.3645x over previous
//
#include <hip/hip_runtime.h>
#include <hip/hip_bf16.h>

typedef _Float16 f16x8 __attribute__((ext_vector_type(8)));
typedef _Float16 f16x4 __attribute__((ext_vector_type(4)));
typedef __fp16 fp16x2 __attribute__((ext_vector_type(2)));
typedef float f32x4 __attribute__((ext_vector_type(4)));

#define BATCH 4
#define SEQ 4096
#define EMB 1024
#define HEAD 64

// Async global->LDS, 16B per lane. LDS dest is WAVE-UNIFORM base; HW adds
// lane*16. Global src is per-lane (we make it base + lane*16 = coalesced).
__device__ __forceinline__ void async_copy16(const void* gsrc, void* ldst) {
  __builtin_amdgcn_global_load_lds(
      (const __attribute__((address_space(1))) void*)gsrc,
      (__attribute__((address_space(3))) void*)ldst,
      16, 0, 0);
}

// ---------------------------------------------------------------------------
// Kernel 1: weights -> glds-tiled WT (unchanged).
// ---------------------------------------------------------------------------
__global__ __launch_bounds__(256) void wtrans_kernel(
    const float* __restrict__ Wk, const float* __restrict__ Wq,
    const float* __restrict__ Wv, _Float16* __restrict__ WT) {
  int id = blockIdx.x * 256 + threadIdx.x;   // 0 .. 24575 (unit index)
  int step = id / 1536;
  int rem = id - step * 1536;
  int G = rem / 192;
  int n = rem - G * 192;
  int sel = n >> 6;
  int col = n & 63;
  const float* src = (sel == 0) ? Wq : (sel == 1) ? Wk : Wv;
  const float scale = (sel == 0) ? 0.03125f : 1.0f;
  f16x8 u;
#pragma unroll
  for (int j = 0; j < 8; ++j) {
    int k = step * 64 + G * 8 + j;
    u[j] = (_Float16)(src[k * 64 + col] * scale);
  }
  *(f16x8*)(WT + (size_t)id * 8) = u;
}

// ---------------------------------------------------------------------------
// Kernel 2: QKV projection (unchanged).
// ---------------------------------------------------------------------------
__global__ __launch_bounds__(256) void proj_kernel(
    const float* __restrict__ x, const _Float16* __restrict__ WT,
    _Float16* __restrict__ Qh, _Float16* __restrict__ KT,
    _Float16* __restrict__ VT) {
  __shared__ _Float16 wtl[2][12288];   // 2 x 24 KB, unit u = G*192 + n
  const int tid = threadIdx.x;
  const int wave = tid >> 6;
  const int lane = tid & 63;
  const int quad = lane >> 4;
  const int l16 = lane & 15;
  const int wm = wave & 1;
  const int wn = wave >> 1;
  const int rowblk = blockIdx.x * 32;

  const float* xr = x + (size_t)(rowblk + wm * 16 + l16) * EMB + quad * 8;

  f32x4 acc[6];
#pragma unroll
  for (int t = 0; t < 6; ++t) acc[t] = (f32x4){0.f, 0.f, 0.f, 0.f};

#pragma unroll
  for (int i = 0; i < 6; ++i) {
    const int c = wave * 6 + i;
    async_copy16(WT + (size_t)c * 512 + lane * 8, (char*)&wtl[0][0] + c * 1024);
  }
  float4 xa = *(const float4*)(xr);
  float4 xb = *(const float4*)(xr + 4);
  float4 xc = *(const float4*)(xr + 32);
  float4 xd = *(const float4*)(xr + 36);
  __syncthreads();

  int p = 0;
  for (int step = 0; step < 16; ++step) {
    if (step < 15) {
      const _Float16* wsrc = WT + (size_t)(step + 1) * 12288;
#pragma unroll
      for (int i = 0; i < 6; ++i) {
        const int c = wave * 6 + i;
        async_copy16(wsrc + (size_t)c * 512 + lane * 8,
                     (char*)&wtl[p ^ 1][0] + c * 1024);
      }
    }
    fp16x2 p0 = __builtin_amdgcn_cvt_pkrtz(xa.x, xa.y);
    fp16x2 p1 = __builtin_amdgcn_cvt_pkrtz(xa.z, xa.w);
    fp16x2 p2 = __builtin_amdgcn_cvt_pkrtz(xb.x, xb.y);
    fp16x2 p3 = __builtin_amdgcn_cvt_pkrtz(xb.z, xb.w);
    f16x8 af0, af1;
    af0[0] = (_Float16)p0[0]; af0[1] = (_Float16)p0[1];
    af0[2] = (_Float16)p1[0]; af0[3] = (_Float16)p1[1];
    af0[4] = (_Float16)p2[0]; af0[5] = (_Float16)p2[1];
    af0[6] = (_Float16)p3[0]; af0[7] = (_Float16)p3[1];
    p0 = __builtin_amdgcn_cvt_pkrtz(xc.x, xc.y);
    p1 = __builtin_amdgcn_cvt_pkrtz(xc.z, xc.w);
    p2 = __builtin_amdgcn_cvt_pkrtz(xd.x, xd.y);
    p3 = __builtin_amdgcn_cvt_pkrtz(xd.z, xd.w);
    af1[0] = (_Float16)p0[0]; af1[1] = (_Float16)p0[1];
    af1[2] = (_Float16)p1[0]; af1[3] = (_Float16)p1[1];
    af1[4] = (_Float16)p2[0]; af1[5] = (_Float16)p2[1];
    af1[6] = (_Float16)p3[0]; af1[7] = (_Float16)p3[1];
    if (step < 15) {
      const float* xn = xr + (step + 1) * 64;
      xa = *(const float4*)(xn);
      xb = *(const float4*)(xn + 4);
      xc = *(const float4*)(xn + 32);
      xd = *(const float4*)(xn + 36);
    }
#pragma unroll
    for (int t = 0; t < 6; ++t) {
      const int n = wn * 96 + t * 16 + l16;
      const f16x8 b0 = *(const f16x8*)&wtl[p][(size_t)((0 * 4 + quad) * 192 + n) * 8];
      const f16x8 b1 = *(const f16x8*)&wtl[p][(size_t)((1 * 4 + quad) * 192 + n) * 8];
      acc[t] = __builtin_amdgcn_mfma_f32_16x16x32_f16(af0, b0, acc[t], 0, 0, 0);
      acc[t] = __builtin_amdgcn_mfma_f32_16x16x32_f16(af1, b1, acc[t], 0, 0, 0);
    }
    __syncthreads();
    p ^= 1;
  }

  const int rowbase = rowblk + wm * 16;
  const int b = rowbase >> 12;
  const int trbase = (rowbase & 4095) + quad * 4;
#pragma unroll
  for (int t = 0; t < 6; ++t) {
    const int g = wn * 6 + t;
    if (g < 4) {                         // Q row-major (scaled via Wq)
      const int h = g * 16 + l16;
#pragma unroll
      for (int r = 0; r < 4; ++r)
        Qh[(size_t)(rowbase + quad * 4 + r) * HEAD + h] = (_Float16)acc[t][r];
    } else if (g < 8) {                  // K -> KT[b][kt][G=h/8][key][h%8]
      const int h = (g - 4) * 16 + l16;
#pragma unroll
      for (int r = 0; r < 4; ++r) {
        const int t0 = trbase + r;
        const size_t ad = ((size_t)((b * 64 + (t0 >> 6)) * 8 + (h >> 3)) * 64 +
                           (t0 & 63)) * 8 + (h & 7);
        KT[ad] = (_Float16)acc[t][r];
      }
    } else {                             // V -> VT[b][kt][Gk=keygrp][h][key%8]
      const int h = (g - 8) * 16 + l16;
      f16x4 pk;
      pk[0] = (_Float16)acc[t][0]; pk[1] = (_Float16)acc[t][1];
      pk[2] = (_Float16)acc[t][2]; pk[3] = (_Float16)acc[t][3];
      const size_t ad = ((size_t)((b * 64 + (trbase >> 6)) * 8 + ((trbase & 63) >> 3)) * 512) +
                        (size_t)h * 8 + (trbase & 7);
      *(f16x4*)(VT + ad) = pk;
    }
  }
}

// ---------------------------------------------------------------------------
// Kernel 3: causal flash attention — wave-private, barrier-free main loop.
// K/V total 2MB/batch = L2-resident (FETCH_SIZE confirms): NO LDS staging,
// K/V fragments load straight from L2 into registers (same frag addressing
// the staged path used). No online max => kt-range is parallel: each 16-row
// q-tile is split across 2 waves (kt halves), O/l partials combined once at
// the end. Block = 4 waves = tiles (j, 255-j) x 2 kt-halves; grid 512 ->
// 2 blocks/CU = 8 waves/CU (2/SIMD), ZERO barriers in the loop.
// V loads issue at step start, consumed after QK+exp (~300cy, self-hiding);
// K prefetched one step ahead (loop-carried). P stays wave-private in LDS
// (stride 68: conflict-free, measured 0 in R3). b = blockIdx&3 -> one batch
// per XCD pair, KV L2-resident.
// ---------------------------------------------------------------------------
__global__ __launch_bounds__(256) void flash_kernel(
    const _Float16* __restrict__ Qh, const _Float16* __restrict__ KT,
    const _Float16* __restrict__ VT, float* __restrict__ out) {
  __shared__ _Float16 myp[4][16 * 68];  // wave-private P, stride 68 halves
  __shared__ float lds_o[2][16][68];    // per-tile O partial (odd wave)
  __shared__ float lds_l[2][16];        // per-tile l partial (odd wave)
  const int tid = threadIdx.x;
  const int w = tid >> 6;
  const int lane = tid & 63;
  const int quad = lane >> 4;
  const int l16 = lane & 15;
  const int b = blockIdx.x & 3;
  const int jj = blockIdx.x >> 2;       // 0..127
  const int t = w >> 1;                 // local tile slot (0,1)
  const int kh = w & 1;                 // kt-range half
  const int j = t ? (255 - jj) : jj;    // tile index within batch
  const int qb = j * 16;
  const int nkt = (j >> 2) + 1;
  const int h1 = (nkt + 1) >> 1;        // split point
  const int lo = kh ? h1 : 0;
  const int hi = kh ? nkt : h1;

  const _Float16* Q = Qh + (size_t)b * SEQ * HEAD;
  const _Float16* KTb = KT + (size_t)b * 64 * 4096;  // 4096 halves per kt
  const _Float16* VTb = VT + (size_t)b * 64 * 4096;
  const f32x4 zero = {0.f, 0.f, 0.f, 0.f};
  _Float16* mp = &myp[w][0];

  // Q A-frags, loaded once
  const f16x8 aq0 = *(const f16x8*)(Q + (size_t)(qb + l16) * HEAD + quad * 8);
  const f16x8 aq1 = *(const f16x8*)(Q + (size_t)(qb + l16) * HEAD + 32 + quad * 8);
  const int qrow = qb + quad * 4;       // +r

  f32x4 oc[4];
#pragma unroll
  for (int m = 0; m < 4; ++m) oc[m] = zero;
  float lacc[4] = {0.f, 0.f, 0.f, 0.f};

  // K frags for first kt (loop-carried prefetch)
  f16x8 ka[4], kb[4];
  if (lo < hi) {
    const _Float16* kp = KTb + (size_t)lo * 4096;
#pragma unroll
    for (int s = 0; s < 4; ++s) {
      ka[s] = *(const f16x8*)(kp + (size_t)quad * 512 + (s * 16 + l16) * 8);
      kb[s] = *(const f16x8*)(kp + (size_t)(4 + quad) * 512 + (s * 16 + l16) * 8);
    }
  }

  for (int kt = lo; kt < hi; ++kt) {
    // V frag loads (consumed after QK+exp — latency self-hiding)
    const _Float16* vp = VTb + (size_t)kt * 4096;
    f16x8 va[4], vb[4];
#pragma unroll
    for (int m = 0; m < 4; ++m) {
      va[m] = *(const f16x8*)(vp + (size_t)quad * 512 + (m * 16 + l16) * 8);
      vb[m] = *(const f16x8*)(vp + (size_t)(4 + quad) * 512 + (m * 16 + l16) * 8);
    }

    // QK: full 64 keys, 4 key-subtiles x (2 MFMA over h=64)
    f32x4 sc[4];
#pragma unroll
    for (int s = 0; s < 4; ++s) {
      sc[s] = __builtin_amdgcn_mfma_f32_16x16x32_f16(aq0, ka[s], zero, 0, 0, 0);
      sc[s] = __builtin_amdgcn_mfma_f32_16x16x32_f16(aq1, kb[s], sc[s], 0, 0, 0);
    }

    // prefetch next step's K (loop-carried, overlaps exp/P/PV)
    if (kt + 1 < hi) {
      const _Float16* kp = KTb + (size_t)(kt + 1) * 4096;
#pragma unroll
      for (int s = 0; s < 4; ++s) {
        ka[s] = *(const f16x8*)(kp + (size_t)quad * 512 + (s * 16 + l16) * 8);
        kb[s] = *(const f16x8*)(kp + (size_t)(4 + quad) * 512 + (s * 16 + l16) * 8);
      }
    }

    // mask (diagonal step only) + exp + wave-private P write
    const int kbase = kt * 64;
    if (kt == nkt - 1) {
#pragma unroll
      for (int s = 0; s < 4; ++s) {
#pragma unroll
        for (int r = 0; r < 4; ++r) {
          const float pv = (kbase + s * 16 + l16 > qrow + r) ? 0.f : __expf(sc[s][r]);
          lacc[r] += pv;
          mp[(quad * 4 + r) * 68 + s * 16 + l16] = (_Float16)pv;
        }
      }
    } else {
#pragma unroll
      for (int s = 0; s < 4; ++s) {
#pragma unroll
        for (int r = 0; r < 4; ++r) {
          const float pv = __expf(sc[s][r]);
          lacc[r] += pv;
          mp[(quad * 4 + r) * 68 + s * 16 + l16] = (_Float16)pv;
        }
      }
    }

    // P A-frags (wave-private round trip, lgkmcnt-ordered, no barrier)
    const f16x8 ap0 = *(const f16x8*)(mp + l16 * 68 + quad * 8);
    const f16x8 ap1 = *(const f16x8*)(mp + l16 * 68 + 32 + quad * 8);

    // PV: 4 h-subtiles x (2 MFMA over k=64)
#pragma unroll
    for (int m = 0; m < 4; ++m) {
      oc[m] = __builtin_amdgcn_mfma_f32_16x16x32_f16(ap0, va[m], oc[m], 0, 0, 0);
      oc[m] = __builtin_amdgcn_mfma_f32_16x16x32_f16(ap1, vb[m], oc[m], 0, 0, 0);
    }
  }

  // reduce row sums over the lane's 16-key slice partners (l16 bits)
  float lr[4];
#pragma unroll
  for (int r = 0; r < 4; ++r) {
    float l = lacc[r];
    l += __shfl_xor(l, 1);
    l += __shfl_xor(l, 2);
    l += __shfl_xor(l, 4);
    l += __shfl_xor(l, 8);
    lr[r] = l;
  }

  // odd wave deposits partials; even wave combines + writes
  if (kh) {
#pragma unroll
    for (int r = 0; r < 4; ++r) {
      if (l16 == 0) lds_l[t][quad * 4 + r] = lr[r];
#pragma unroll
      for (int m = 0; m < 4; ++m)
        lds_o[t][quad * 4 + r][m * 16 + l16] = oc[m][r];
    }
  }
  __syncthreads();
  if (!kh) {
#pragma unroll
    for (int r = 0; r < 4; ++r) {
      const float lsum = lr[r] + lds_l[t][quad * 4 + r];
      const float inv = 1.0f / lsum;
      float* op = out + ((size_t)b * SEQ + qb + quad * 4 + r) * HEAD + l16;
#pragma unroll
      for (int m = 0; m < 4; ++m)
        op[m * 16] = (oc[m][r] + lds_o[t][quad * 4 + r][m * 16 + l16]) * inv;
    }
  }
}

extern "C" void kernel_launch(void* const* d_in, const int* in_sizes, int n_in,
                              void* d_out, int out_size, void* d_ws, size_t ws_size,
                              hipStream_t stream) {
  const float* x  = (const float*)d_in[0];
  const float* Wk = (const float*)d_in[1];
  const float* Wq = (const float*)d_in[2];
  const float* Wv = (const float*)d_in[3];
  float* out = (float*)d_out;

  // ws layout: Qh[0,2MB) KT[2MB,4MB) VT[4MB,6MB) WT[6MB,6.375MB)
  char* ws = (char*)d_ws;
  _Float16* Qh = (_Float16*)(ws);
  _Float16* KT = (_Float16*)(ws + (size_t)2 * 1024 * 1024);
  _Float16* VT = (_Float16*)(ws + (size_t)4 * 1024 * 1024);
  _Float16* WT = (_Float16*)(ws + (size_t)6 * 1024 * 1024);

  wtrans_kernel<<<96, 256, 0, stream>>>(Wk, Wq, Wv, WT);
  proj_kernel<<<512, 256, 0, stream>>>(x, WT, Qh, KT, VT);
  flash_kernel<<<512, 256, 0, stream>>>(Qh, KT, VT, out);
}

// Round 5
// 136.678 us; speedup vs baseline: 1.4347x; 1.0514x over previous
//
#include <hip/hip_runtime.h>
#include <hip/hip_bf16.h>

typedef _Float16 f16x8 __attribute__((ext_vector_type(8)));
typedef _Float16 f16x4 __attribute__((ext_vector_type(4)));
typedef __fp16 fp16x2 __attribute__((ext_vector_type(2)));
typedef float f32x4 __attribute__((ext_vector_type(4)));

#define BATCH 4
#define SEQ 4096
#define EMB 1024
#define HEAD 64

// Async global->LDS, 16B per lane. LDS dest is WAVE-UNIFORM base; HW adds
// lane*16. Global src is per-lane (we make it base + lane*16 = coalesced,
// or pre-swizzled for conflict-free LDS reads — m173 pattern).
__device__ __forceinline__ void async_copy16(const void* gsrc, void* ldst) {
  __builtin_amdgcn_global_load_lds(
      (const __attribute__((address_space(1))) void*)gsrc,
      (__attribute__((address_space(3))) void*)ldst,
      16, 0, 0);
}

// ---------------------------------------------------------------------------
// Kernel 1: weights -> glds-tiled WT (unchanged).
// ---------------------------------------------------------------------------
__global__ __launch_bounds__(256) void wtrans_kernel(
    const float* __restrict__ Wk, const float* __restrict__ Wq,
    const float* __restrict__ Wv, _Float16* __restrict__ WT) {
  int id = blockIdx.x * 256 + threadIdx.x;   // 0 .. 24575 (unit index)
  int step = id / 1536;
  int rem = id - step * 1536;
  int G = rem / 192;
  int n = rem - G * 192;
  int sel = n >> 6;
  int col = n & 63;
  const float* src = (sel == 0) ? Wq : (sel == 1) ? Wk : Wv;
  const float scale = (sel == 0) ? 0.03125f : 1.0f;
  f16x8 u;
#pragma unroll
  for (int j = 0; j < 8; ++j) {
    int k = step * 64 + G * 8 + j;
    u[j] = (_Float16)(src[k * 64 + col] * scale);
  }
  *(f16x8*)(WT + (size_t)id * 8) = u;
}

// ---------------------------------------------------------------------------
// Kernel 2: QKV projection. M=32 tile, grid 512 (2 blocks/CU), 4 waves 2x2.
// BK=64, 16 steps, ONE barrier/step. BOTH operands now glds-staged and
// double-buffered:
//   WT: 24 KB/step, 6 coalesced 1KB chunks/wave (unchanged).
//   x:  8 KB/step ([32 rows][64 floats] linear LDS), 2 chunks/wave, with
//       16B-unit XOR swizzle (u ^= row&7) applied on the GLOBAL source and
//       the LDS read (both-sides involution) -> reads are ~2-way = free.
// This removes the loop-carried register x-prefetch whose codegen was
// regalloc-dependent (R4: VGPR 168->68 from an unrelated flash edit => +9us).
// Staging issues at step start, drains at the step barrier -> latency hides
// under MFMA/LDS work deterministically.
// ---------------------------------------------------------------------------
__global__ __launch_bounds__(256) void proj_kernel(
    const float* __restrict__ x, const _Float16* __restrict__ WT,
    _Float16* __restrict__ Qh, _Float16* __restrict__ KT,
    _Float16* __restrict__ VT) {
  __shared__ _Float16 wtl[2][12288];   // 2 x 24 KB, unit u = G*192 + n
  __shared__ float xls[2][32 * 64];    // 2 x 8 KB x tile, swizzled units
  const int tid = threadIdx.x;
  const int wave = tid >> 6;
  const int lane = tid & 63;
  const int quad = lane >> 4;
  const int l16 = lane & 15;
  const int wm = wave & 1;
  const int wn = wave >> 1;
  const int rowblk = blockIdx.x * 32;

  // x staging geometry: chunk c covers tile rows 4c..4c+3; lane -> row
  // 4c + (lane>>4), LDS unit position pos = lane&15; global unit
  // u = pos ^ (row&7) (involution; read applies the same XOR).
  const int lq = lane >> 4;
  const int pos = lane & 15;

  f32x4 acc[6];
#pragma unroll
  for (int t = 0; t < 6; ++t) acc[t] = (f32x4){0.f, 0.f, 0.f, 0.f};

  // stage step 0: WT (6 chunks/wave) + x (2 chunks/wave)
#pragma unroll
  for (int i = 0; i < 6; ++i) {
    const int c = wave * 6 + i;
    async_copy16(WT + (size_t)c * 512 + lane * 8, (char*)&wtl[0][0] + c * 1024);
  }
#pragma unroll
  for (int i = 0; i < 2; ++i) {
    const int c = wave * 2 + i;
    const int rt = c * 4 + lq;
    const int u = pos ^ (rt & 7);
    async_copy16(x + (size_t)(rowblk + rt) * EMB + u * 4,
                 (char*)&xls[0][0] + c * 1024);
  }
  __syncthreads();

  // read-side swizzled x offsets (tile-local row rt, 16B units)
  const int rt = wm * 16 + l16;
  const int rb = rt & 7;
  const int ua = ((quad * 2) ^ rb) * 4;        // floats [quad*8,   +4)
  const int ub = ((quad * 2 + 1) ^ rb) * 4;    // floats [quad*8+4, +4)
  const int uc = ((8 + quad * 2) ^ rb) * 4;    // floats [quad*8+32, +4)
  const int ud = ((8 + quad * 2 + 1) ^ rb) * 4;

  int p = 0;
  for (int step = 0; step < 16; ++step) {
    // stage next step's WT + x into the other buffer (overlaps compute)
    if (step < 15) {
      const _Float16* wsrc = WT + (size_t)(step + 1) * 12288;
#pragma unroll
      for (int i = 0; i < 6; ++i) {
        const int c = wave * 6 + i;
        async_copy16(wsrc + (size_t)c * 512 + lane * 8,
                     (char*)&wtl[p ^ 1][0] + c * 1024);
      }
      const float* xsrc = x + (size_t)(step + 1) * 64;
#pragma unroll
      for (int i = 0; i < 2; ++i) {
        const int c = wave * 2 + i;
        const int rts = c * 4 + lq;
        const int u = pos ^ (rts & 7);
        async_copy16(xsrc + (size_t)(rowblk + rts) * EMB + u * 4,
                     (char*)&xls[p ^ 1][0] + c * 1024);
      }
    }
    // x frags from LDS (swizzled float4 reads, ~2-way = free)
    const float* xl = &xls[p][rt * 64];
    const float4 xa = *(const float4*)(xl + ua);
    const float4 xb = *(const float4*)(xl + ub);
    const float4 xc = *(const float4*)(xl + uc);
    const float4 xd = *(const float4*)(xl + ud);
    fp16x2 p0 = __builtin_amdgcn_cvt_pkrtz(xa.x, xa.y);
    fp16x2 p1 = __builtin_amdgcn_cvt_pkrtz(xa.z, xa.w);
    fp16x2 p2 = __builtin_amdgcn_cvt_pkrtz(xb.x, xb.y);
    fp16x2 p3 = __builtin_amdgcn_cvt_pkrtz(xb.z, xb.w);
    f16x8 af0, af1;
    af0[0] = (_Float16)p0[0]; af0[1] = (_Float16)p0[1];
    af0[2] = (_Float16)p1[0]; af0[3] = (_Float16)p1[1];
    af0[4] = (_Float16)p2[0]; af0[5] = (_Float16)p2[1];
    af0[6] = (_Float16)p3[0]; af0[7] = (_Float16)p3[1];
    p0 = __builtin_amdgcn_cvt_pkrtz(xc.x, xc.y);
    p1 = __builtin_amdgcn_cvt_pkrtz(xc.z, xc.w);
    p2 = __builtin_amdgcn_cvt_pkrtz(xd.x, xd.y);
    p3 = __builtin_amdgcn_cvt_pkrtz(xd.z, xd.w);
    af1[0] = (_Float16)p0[0]; af1[1] = (_Float16)p0[1];
    af1[2] = (_Float16)p1[0]; af1[3] = (_Float16)p1[1];
    af1[4] = (_Float16)p2[0]; af1[5] = (_Float16)p2[1];
    af1[6] = (_Float16)p3[0]; af1[7] = (_Float16)p3[1];
    // compute: 12 B-frag LDS reads + 12 MFMA
#pragma unroll
    for (int t = 0; t < 6; ++t) {
      const int n = wn * 96 + t * 16 + l16;
      const f16x8 b0 = *(const f16x8*)&wtl[p][(size_t)((0 * 4 + quad) * 192 + n) * 8];
      const f16x8 b1 = *(const f16x8*)&wtl[p][(size_t)((1 * 4 + quad) * 192 + n) * 8];
      acc[t] = __builtin_amdgcn_mfma_f32_16x16x32_f16(af0, b0, acc[t], 0, 0, 0);
      acc[t] = __builtin_amdgcn_mfma_f32_16x16x32_f16(af1, b1, acc[t], 0, 0, 0);
    }
    __syncthreads();
    p ^= 1;
  }

  // Epilogue. C-layout: row = rowbase + quad*4 + r, col(l16) within tile.
  const int rowbase = rowblk + wm * 16;
  const int b = rowbase >> 12;
  const int trbase = (rowbase & 4095) + quad * 4;
#pragma unroll
  for (int t = 0; t < 6; ++t) {
    const int g = wn * 6 + t;
    if (g < 4) {                         // Q row-major (scaled via Wq)
      const int h = g * 16 + l16;
#pragma unroll
      for (int r = 0; r < 4; ++r)
        Qh[(size_t)(rowbase + quad * 4 + r) * HEAD + h] = (_Float16)acc[t][r];
    } else if (g < 8) {                  // K -> KT[b][kt][G=h/8][key][h%8]
      const int h = (g - 4) * 16 + l16;
#pragma unroll
      for (int r = 0; r < 4; ++r) {
        const int t0 = trbase + r;
        const size_t ad = ((size_t)((b * 64 + (t0 >> 6)) * 8 + (h >> 3)) * 64 +
                           (t0 & 63)) * 8 + (h & 7);
        KT[ad] = (_Float16)acc[t][r];
      }
    } else {                             // V -> VT[b][kt][Gk=keygrp][h][key%8]
      const int h = (g - 8) * 16 + l16;
      f16x4 pk;
      pk[0] = (_Float16)acc[t][0]; pk[1] = (_Float16)acc[t][1];
      pk[2] = (_Float16)acc[t][2]; pk[3] = (_Float16)acc[t][3];
      const size_t ad = ((size_t)((b * 64 + (trbase >> 6)) * 8 + ((trbase & 63) >> 3)) * 512) +
                        (size_t)h * 8 + (trbase & 7);
      *(f16x4*)(VT + ad) = pk;
    }
  }
}

// ---------------------------------------------------------------------------
// Kernel 3: causal flash attention — wave-private, barrier-free main loop
// (unchanged from R4: < 40.7 us, dropped out of profile top-5).
// ---------------------------------------------------------------------------
__global__ __launch_bounds__(256) void flash_kernel(
    const _Float16* __restrict__ Qh, const _Float16* __restrict__ KT,
    const _Float16* __restrict__ VT, float* __restrict__ out) {
  __shared__ _Float16 myp[4][16 * 68];  // wave-private P, stride 68 halves
  __shared__ float lds_o[2][16][68];    // per-tile O partial (odd wave)
  __shared__ float lds_l[2][16];        // per-tile l partial (odd wave)
  const int tid = threadIdx.x;
  const int w = tid >> 6;
  const int lane = tid & 63;
  const int quad = lane >> 4;
  const int l16 = lane & 15;
  const int b = blockIdx.x & 3;
  const int jj = blockIdx.x >> 2;       // 0..127
  const int t = w >> 1;                 // local tile slot (0,1)
  const int kh = w & 1;                 // kt-range half
  const int j = t ? (255 - jj) : jj;    // tile index within batch
  const int qb = j * 16;
  const int nkt = (j >> 2) + 1;
  const int h1 = (nkt + 1) >> 1;        // split point
  const int lo = kh ? h1 : 0;
  const int hi = kh ? nkt : h1;

  const _Float16* Q = Qh + (size_t)b * SEQ * HEAD;
  const _Float16* KTb = KT + (size_t)b * 64 * 4096;  // 4096 halves per kt
  const _Float16* VTb = VT + (size_t)b * 64 * 4096;
  const f32x4 zero = {0.f, 0.f, 0.f, 0.f};
  _Float16* mp = &myp[w][0];

  // Q A-frags, loaded once
  const f16x8 aq0 = *(const f16x8*)(Q + (size_t)(qb + l16) * HEAD + quad * 8);
  const f16x8 aq1 = *(const f16x8*)(Q + (size_t)(qb + l16) * HEAD + 32 + quad * 8);
  const int qrow = qb + quad * 4;       // +r

  f32x4 oc[4];
#pragma unroll
  for (int m = 0; m < 4; ++m) oc[m] = zero;
  float lacc[4] = {0.f, 0.f, 0.f, 0.f};

  // K frags for first kt (loop-carried prefetch)
  f16x8 ka[4], kb[4];
  if (lo < hi) {
    const _Float16* kp = KTb + (size_t)lo * 4096;
#pragma unroll
    for (int s = 0; s < 4; ++s) {
      ka[s] = *(const f16x8*)(kp + (size_t)quad * 512 + (s * 16 + l16) * 8);
      kb[s] = *(const f16x8*)(kp + (size_t)(4 + quad) * 512 + (s * 16 + l16) * 8);
    }
  }

  for (int kt = lo; kt < hi; ++kt) {
    // V frag loads (consumed after QK+exp — latency self-hiding)
    const _Float16* vp = VTb + (size_t)kt * 4096;
    f16x8 va[4], vb[4];
#pragma unroll
    for (int m = 0; m < 4; ++m) {
      va[m] = *(const f16x8*)(vp + (size_t)quad * 512 + (m * 16 + l16) * 8);
      vb[m] = *(const f16x8*)(vp + (size_t)(4 + quad) * 512 + (m * 16 + l16) * 8);
    }

    // QK: full 64 keys, 4 key-subtiles x (2 MFMA over h=64)
    f32x4 sc[4];
#pragma unroll
    for (int s = 0; s < 4; ++s) {
      sc[s] = __builtin_amdgcn_mfma_f32_16x16x32_f16(aq0, ka[s], zero, 0, 0, 0);
      sc[s] = __builtin_amdgcn_mfma_f32_16x16x32_f16(aq1, kb[s], sc[s], 0, 0, 0);
    }

    // prefetch next step's K (loop-carried, overlaps exp/P/PV)
    if (kt + 1 < hi) {
      const _Float16* kp = KTb + (size_t)(kt + 1) * 4096;
#pragma unroll
      for (int s = 0; s < 4; ++s) {
        ka[s] = *(const f16x8*)(kp + (size_t)quad * 512 + (s * 16 + l16) * 8);
        kb[s] = *(const f16x8*)(kp + (size_t)(4 + quad) * 512 + (s * 16 + l16) * 8);
      }
    }

    // mask (diagonal step only) + exp + wave-private P write
    const int kbase = kt * 64;
    if (kt == nkt - 1) {
#pragma unroll
      for (int s = 0; s < 4; ++s) {
#pragma unroll
        for (int r = 0; r < 4; ++r) {
          const float pv = (kbase + s * 16 + l16 > qrow + r) ? 0.f : __expf(sc[s][r]);
          lacc[r] += pv;
          mp[(quad * 4 + r) * 68 + s * 16 + l16] = (_Float16)pv;
        }
      }
    } else {
#pragma unroll
      for (int s = 0; s < 4; ++s) {
#pragma unroll
        for (int r = 0; r < 4; ++r) {
          const float pv = __expf(sc[s][r]);
          lacc[r] += pv;
          mp[(quad * 4 + r) * 68 + s * 16 + l16] = (_Float16)pv;
        }
      }
    }

    // P A-frags (wave-private round trip, lgkmcnt-ordered, no barrier)
    const f16x8 ap0 = *(const f16x8*)(mp + l16 * 68 + quad * 8);
    const f16x8 ap1 = *(const f16x8*)(mp + l16 * 68 + 32 + quad * 8);

    // PV: 4 h-subtiles x (2 MFMA over k=64)
#pragma unroll
    for (int m = 0; m < 4; ++m) {
      oc[m] = __builtin_amdgcn_mfma_f32_16x16x32_f16(ap0, va[m], oc[m], 0, 0, 0);
      oc[m] = __builtin_amdgcn_mfma_f32_16x16x32_f16(ap1, vb[m], oc[m], 0, 0, 0);
    }
  }

  // reduce row sums over the lane's 16-key slice partners (l16 bits)
  float lr[4];
#pragma unroll
  for (int r = 0; r < 4; ++r) {
    float l = lacc[r];
    l += __shfl_xor(l, 1);
    l += __shfl_xor(l, 2);
    l += __shfl_xor(l, 4);
    l += __shfl_xor(l, 8);
    lr[r] = l;
  }

  // odd wave deposits partials; even wave combines + writes
  if (kh) {
#pragma unroll
    for (int r = 0; r < 4; ++r) {
      if (l16 == 0) lds_l[t][quad * 4 + r] = lr[r];
#pragma unroll
      for (int m = 0; m < 4; ++m)
        lds_o[t][quad * 4 + r][m * 16 + l16] = oc[m][r];
    }
  }
  __syncthreads();
  if (!kh) {
#pragma unroll
    for (int r = 0; r < 4; ++r) {
      const float lsum = lr[r] + lds_l[t][quad * 4 + r];
      const float inv = 1.0f / lsum;
      float* op = out + ((size_t)b * SEQ + qb + quad * 4 + r) * HEAD + l16;
#pragma unroll
      for (int m = 0; m < 4; ++m)
        op[m * 16] = (oc[m][r] + lds_o[t][quad * 4 + r][m * 16 + l16]) * inv;
    }
  }
}

extern "C" void kernel_launch(void* const* d_in, const int* in_sizes, int n_in,
                              void* d_out, int out_size, void* d_ws, size_t ws_size,
                              hipStream_t stream) {
  const float* x  = (const float*)d_in[0];
  const float* Wk = (const float*)d_in[1];
  const float* Wq = (const float*)d_in[2];
  const float* Wv = (const float*)d_in[3];
  float* out = (float*)d_out;

  // ws layout: Qh[0,2MB) KT[2MB,4MB) VT[4MB,6MB) WT[6MB,6.375MB)
  char* ws = (char*)d_ws;
  _Float16* Qh = (_Float16*)(ws);
  _Float16* KT = (_Float16*)(ws + (size_t)2 * 1024 * 1024);
  _Float16* VT = (_Float16*)(ws + (size_t)4 * 1024 * 1024);
  _Float16* WT = (_Float16*)(ws + (size_t)6 * 1024 * 1024);

  wtrans_kernel<<<96, 256, 0, stream>>>(Wk, Wq, Wv, WT);
  proj_kernel<<<512, 256, 0, stream>>>(x, WT, Qh, KT, VT);
  flash_kernel<<<512, 256, 0, stream>>>(Qh, KT, VT, out);
}